// Round 13
// baseline (288.978 us; speedup 1.0000x reference)
//
#include <hip/hip_runtime.h>
#include <stdint.h>

#define NB 16
#define NS 4096
#define NH 16
#define NC 1024

// ---- workspace layout (float offsets) ----
#define OFF_QHP   0u          // 262144   qhp[cs16][b][d]
#define OFF_QK    262144u     // 262144   qk[b][h][c]
#define OFF_QB    524288u     // 256      qb[b][h]
#define OFF_SP    524608u     // 8192     Sp[b][sb16][ph32]
#define OFF_CTXP  532800u     // 8388608  ctxp[sb16*2+p][b][h][c]
#define OFF_CON   8921408u    // 32768    concat[p][b][dm]

// qhp[cs][b][d] = sum_{c in cs-chunk} q[b][c] * Wq[c][d]
__global__ __launch_bounds__(128) void k_qh(
    const float* __restrict__ q, const float* __restrict__ Wq, float* __restrict__ qhp)
{
    __shared__ float qs[64*16];   // [c][b]
    int dz = blockIdx.x, cs = blockIdx.y;
    int tid = threadIdx.x;
    int d = dz*128 + tid;
#pragma unroll
    for (int j = 0; j < 2; ++j) {
        int idx = j*128 + tid;
        int b = idx >> 4, c4 = (idx & 15) << 2;
        float4 t = *(const float4*)(q + (size_t)b*NC + cs*64 + c4);
        qs[(c4+0)*16 + b] = t.x; qs[(c4+1)*16 + b] = t.y;
        qs[(c4+2)*16 + b] = t.z; qs[(c4+3)*16 + b] = t.w;
    }
    __syncthreads();
    float acc[16];
#pragma unroll
    for (int b = 0; b < 16; ++b) acc[b] = 0.f;
#pragma unroll 4
    for (int c = 0; c < 64; ++c) {
        float w = Wq[(size_t)(cs*64 + c)*NC + d];
        const float4* qr = (const float4*)(qs + c*16);
        float4 q0 = qr[0], q1 = qr[1], q2 = qr[2], q3 = qr[3];
        acc[0]  = fmaf(w, q0.x, acc[0]);  acc[1]  = fmaf(w, q0.y, acc[1]);
        acc[2]  = fmaf(w, q0.z, acc[2]);  acc[3]  = fmaf(w, q0.w, acc[3]);
        acc[4]  = fmaf(w, q1.x, acc[4]);  acc[5]  = fmaf(w, q1.y, acc[5]);
        acc[6]  = fmaf(w, q1.z, acc[6]);  acc[7]  = fmaf(w, q1.w, acc[7]);
        acc[8]  = fmaf(w, q2.x, acc[8]);  acc[9]  = fmaf(w, q2.y, acc[9]);
        acc[10] = fmaf(w, q2.z, acc[10]); acc[11] = fmaf(w, q2.w, acc[11]);
        acc[12] = fmaf(w, q3.x, acc[12]); acc[13] = fmaf(w, q3.y, acc[13]);
        acc[14] = fmaf(w, q3.z, acc[14]); acc[15] = fmaf(w, q3.w, acc[15]);
    }
#pragma unroll
    for (int b = 0; b < 16; ++b) qhp[((size_t)cs*16 + b)*NC + d] = acc[b];
}

// qk[b][h][c] = sum_d qh[b][h64+d]*Wk[c][h64+d];  qh = sum_cs qhp + bq. qb = qh_h . bk_h
__global__ __launch_bounds__(128) void k_qk(
    const float* __restrict__ qhp, const float* __restrict__ bq,
    const float* __restrict__ Wk, const float* __restrict__ bk,
    float* __restrict__ qko, float* __restrict__ qbv)
{
    int h = blockIdx.x;
    int c = blockIdx.y*128 + threadIdx.x;
    __shared__ float qs[16*64];   // [b][dd]
    for (int j = 0; j < 8; ++j) {
        int idx = j*128 + threadIdx.x;
        int b = idx >> 6, dd = idx & 63;
        float a = bq[h*64 + dd];
#pragma unroll
        for (int cs = 0; cs < 16; ++cs) a += qhp[((size_t)cs*16 + b)*NC + h*64 + dd];
        qs[idx] = a;
    }
    __syncthreads();
    const float* wr = Wk + (size_t)c*NC + h*64;
    float acc[16];
#pragma unroll
    for (int b = 0; b < 16; ++b) acc[b] = 0.f;
#pragma unroll 4
    for (int d = 0; d < 64; ++d) {
        float w = wr[d];
#pragma unroll
        for (int b = 0; b < 16; ++b) acc[b] = fmaf(qs[b*64 + d], w, acc[b]);
    }
#pragma unroll
    for (int b = 0; b < 16; ++b) qko[((size_t)b*NH + h)*NC + c] = acc[b];
    if (blockIdx.y == 0 && threadIdx.x < 16) {
        int b = threadIdx.x; float a = 0.f;
        for (int d = 0; d < 64; ++d) a = fmaf(qs[b*64 + d], bk[h*64 + d], a);
        qbv[b*NH + h] = a;
    }
}

// Fused flash-style: scores + exp + mask + (att in LDS) + ctx + S.
// grid (sb=16, b=16) = 256 blocks x 512 thr = 1 block/CU, 2 waves/SIMD.
// Phase A: quad owns 8 rows x 4 heads; depth-2 k prefetch (A/B/T rotation).
// Phase B: half-block owns one p (16 ph, cacc[16][4]); v row prefetch; no reduce.
#define QTS 20
#define SCOMP(BUF, W)                                                          \
    _Pragma("unroll")                                                          \
    for (int j = 0; j < 4; ++j) {                                              \
        const float* qp = qt + ((W)*16 + ph*4 + j)*QTS + hg*4;                 \
        float4 qv = *(const float4*)qp;                                        \
        _Pragma("unroll")                                                      \
        for (int i = 0; i < 8; ++i) {                                          \
            float kc = (j == 0) ? BUF[i].x : (j == 1) ? BUF[i].y               \
                     : (j == 2) ? BUF[i].z : BUF[i].w;                         \
            acc[i][0] = fmaf(kc, qv.x, acc[i][0]);                             \
            acc[i][1] = fmaf(kc, qv.y, acc[i][1]);                             \
            acc[i][2] = fmaf(kc, qv.z, acc[i][2]);                             \
            acc[i][3] = fmaf(kc, qv.w, acc[i][3]);                             \
        }                                                                      \
    }
__global__ __launch_bounds__(512, 2) void k_att(
    const float* __restrict__ kk, const float* __restrict__ vv,
    const float* __restrict__ qkm, const float* __restrict__ qbv,
    const void* __restrict__ mask, float* __restrict__ ctxp, float* __restrict__ Sp)
{
    __shared__ float qt[512*QTS];     // 40 KB q-stage
    __shared__ float attl[256*32];    // 32 KB, XOR-swizzled by row
    __shared__ float red[8][2][16];
    int sb = blockIdx.x, b = blockIdx.y;
    int tid = threadIdx.x;
    int ph = tid & 3, hg = (tid >> 2) & 3, rg = tid >> 4;  // rg in [0,32)
    int srow = sb*256 + rg*8;

    // inline mask dtype probe: 0=int32, 1=bytes, 2=float32
    int fl;
    {
        const uint4* mw = (const uint4*)mask;
        unsigned f = 0u, g = 0u;
#pragma unroll
        for (int j = 0; j < 8; ++j) {
            uint4 m4 = mw[j];
            f |= (m4.x == 0x3F800000u) | (m4.y == 0x3F800000u)
               | (m4.z == 0x3F800000u) | (m4.w == 0x3F800000u);
            g |= ((m4.x > 1u) & (m4.x != 0x3F800000u))
               | ((m4.y > 1u) & (m4.y != 0x3F800000u))
               | ((m4.z > 1u) & (m4.z != 0x3F800000u))
               | ((m4.w > 1u) & (m4.w != 0x3F800000u));
        }
        fl = f ? 2 : (g ? 1 : 0);
    }

    // ---------- Phase A: scores ----------
    const float* kr = kk + ((size_t)b*NS + srow)*NC + ph*4;
    float acc[8][4];
#pragma unroll
    for (int i = 0; i < 8; ++i)
#pragma unroll
        for (int j = 0; j < 4; ++j) acc[i][j] = 0.f;

    for (int cz = 0; cz < 2; ++cz) {
        __syncthreads();
#pragma unroll
        for (int j = 0; j < 16; ++j) {        // stage 512c x 16h
            int idx = j*512 + tid;
            int h = idx >> 9, c = idx & 511;
            qt[c*QTS + h] = qkm[((size_t)b*NH + h)*NC + cz*512 + c];
        }
        __syncthreads();
        const float* kc0 = kr + cz*512;
        float4 A[8], B[8], T[8];
#pragma unroll
        for (int i = 0; i < 8; ++i) A[i] = *(const float4*)(kc0 + i*NC);
#pragma unroll
        for (int i = 0; i < 8; ++i) B[i] = *(const float4*)(kc0 + i*NC + 16);
        for (int w = 0; w < 32; w += 2) {
            if (w + 2 < 32) {
#pragma unroll
                for (int i = 0; i < 8; ++i)
                    T[i] = *(const float4*)(kc0 + i*NC + (w+2)*16);
            }
            SCOMP(A, w);
            if (w + 3 < 32) {
#pragma unroll
                for (int i = 0; i < 8; ++i)
                    A[i] = *(const float4*)(kc0 + i*NC + (w+3)*16);
            }
            SCOMP(B, (w+1));
#pragma unroll
            for (int i = 0; i < 8; ++i) { B[i] = A[i]; A[i] = T[i]; }
        }
    }
#pragma unroll
    for (int i = 0; i < 8; ++i)
#pragma unroll
        for (int j = 0; j < 4; ++j) {
            acc[i][j] += __shfl_xor(acc[i][j], 1, 64);
            acc[i][j] += __shfl_xor(acc[i][j], 2, 64);
        }
    float d0[4], d1[4];
    if (ph == 0) {
#pragma unroll
        for (int j = 0; j < 4; ++j) { d0[j] = acc[0][j]; d1[j] = acc[1][j]; }
    } else if (ph == 1) {
#pragma unroll
        for (int j = 0; j < 4; ++j) { d0[j] = acc[2][j]; d1[j] = acc[3][j]; }
    } else if (ph == 2) {
#pragma unroll
        for (int j = 0; j < 4; ++j) { d0[j] = acc[4][j]; d1[j] = acc[5][j]; }
    } else {
#pragma unroll
        for (int j = 0; j < 4; ++j) { d0[j] = acc[6][j]; d1[j] = acc[7][j]; }
    }
    int lA = rg*8 + 2*ph, lB = lA + 1;
    int sA = sb*256 + lA, sB = sA + 1;
    unsigned mA = 0, mB = 0;
    if (fl == 1) {
        const uint8_t* mp = (const uint8_t*)mask + (size_t)(b*NH + hg*4)*NS;
#pragma unroll
        for (int j = 0; j < 4; ++j) {
            if (mp[(size_t)j*NS + sA]) mA |= (1u << j);
            if (mp[(size_t)j*NS + sB]) mB |= (1u << j);
        }
    } else if (fl == 2) {
        const float* mp = (const float*)mask + (size_t)(b*NH + hg*4)*NS;
#pragma unroll
        for (int j = 0; j < 4; ++j) {
            if (mp[(size_t)j*NS + sA] != 0.f) mA |= (1u << j);
            if (mp[(size_t)j*NS + sB] != 0.f) mB |= (1u << j);
        }
    } else {
        const int* mp = (const int*)mask + (size_t)(b*NH + hg*4)*NS;
#pragma unroll
        for (int j = 0; j < 4; ++j) {
            if (mp[(size_t)j*NS + sA]) mA |= (1u << j);
            if (mp[(size_t)j*NS + sB]) mB |= (1u << j);
        }
    }
    float p0a[4], p1a[4], p0b[4], p1b[4], r0[4], r1[4];
#pragma unroll
    for (int j = 0; j < 4; ++j) {
        float qb = qbv[b*NH + hg*4 + j];
        float va = (d0[j] + qb) * 0.125f;
        float vb = (d1[j] + qb) * 0.125f;
        p0a[j] = __expf(va);  p1a[j] = (mA >> j & 1u) ? 1.0f : p0a[j];
        p0b[j] = __expf(vb);  p1b[j] = (mB >> j & 1u) ? 1.0f : p0b[j];
        r0[j] = p0a[j] + p0b[j];
        r1[j] = p1a[j] + p1b[j];
    }
    // att -> LDS, XOR-swizzled: float-group G (G=hg for p0, 4+hg for p1) of
    // row l lives at attl[l*32 + 4*(G ^ (l&7))]
    {
        int swA = (lA & 7) << 2, swB = (lB & 7) << 2;
        *(float4*)(attl + lA*32 + ((hg*4) ^ swA))        = make_float4(p0a[0], p0a[1], p0a[2], p0a[3]);
        *(float4*)(attl + lA*32 + ((16 + hg*4) ^ swA))   = make_float4(p1a[0], p1a[1], p1a[2], p1a[3]);
        *(float4*)(attl + lB*32 + ((hg*4) ^ swB))        = make_float4(p0b[0], p0b[1], p0b[2], p0b[3]);
        *(float4*)(attl + lB*32 + ((16 + hg*4) ^ swB))   = make_float4(p1b[0], p1b[1], p1b[2], p1b[3]);
    }
    // S partials: xor {1,2} over ph, {16,32} over rg-in-wave, LDS over 8 waves
#pragma unroll
    for (int j = 0; j < 4; ++j) {
        r0[j] += __shfl_xor(r0[j], 1, 64);  r1[j] += __shfl_xor(r1[j], 1, 64);
        r0[j] += __shfl_xor(r0[j], 2, 64);  r1[j] += __shfl_xor(r1[j], 2, 64);
        r0[j] += __shfl_xor(r0[j], 16, 64); r1[j] += __shfl_xor(r1[j], 16, 64);
        r0[j] += __shfl_xor(r0[j], 32, 64); r1[j] += __shfl_xor(r1[j], 32, 64);
    }
    int wv = tid >> 6;
    if ((tid & 51) == 0) {
#pragma unroll
        for (int j = 0; j < 4; ++j) {
            red[wv][0][hg*4 + j] = r0[j];
            red[wv][1][hg*4 + j] = r1[j];
        }
    }
    __syncthreads();     // red + attl ready
    if (tid < 32) {
        int pa = tid >> 4, h = tid & 15;
        float a = 0.f;
#pragma unroll
        for (int w8 = 0; w8 < 8; ++w8) a += red[w8][pa][h];
        Sp[((size_t)b*16 + sb)*32 + tid] = a;
    }

    // ---------- Phase B: ctx (ph-split: half owns p=half) ----------
    int cq = tid & 255, half = tid >> 8;
    float cacc[16][4];
#pragma unroll
    for (int u = 0; u < 16; ++u)
#pragma unroll
        for (int j = 0; j < 4; ++j) cacc[u][j] = 0.f;
    const float* vb = vv + ((size_t)b*NS + sb*256)*NC + cq*4;
    float4 vcur = *(const float4*)vb;
    for (int r = 0; r < 256; ++r) {
        float4 vnxt;
        if (r < 255) vnxt = *(const float4*)(vb + (size_t)(r+1)*NC);
        const float* ar = attl + r*32;
        int lw = r & 7;
#pragma unroll
        for (int g = 0; g < 4; ++g) {
            int G = half*4 + g;
            float4 aw = *(const float4*)(ar + ((G ^ lw) << 2));
            cacc[g*4+0][0] = fmaf(aw.x, vcur.x, cacc[g*4+0][0]);
            cacc[g*4+0][1] = fmaf(aw.x, vcur.y, cacc[g*4+0][1]);
            cacc[g*4+0][2] = fmaf(aw.x, vcur.z, cacc[g*4+0][2]);
            cacc[g*4+0][3] = fmaf(aw.x, vcur.w, cacc[g*4+0][3]);
            cacc[g*4+1][0] = fmaf(aw.y, vcur.x, cacc[g*4+1][0]);
            cacc[g*4+1][1] = fmaf(aw.y, vcur.y, cacc[g*4+1][1]);
            cacc[g*4+1][2] = fmaf(aw.y, vcur.z, cacc[g*4+1][2]);
            cacc[g*4+1][3] = fmaf(aw.y, vcur.w, cacc[g*4+1][3]);
            cacc[g*4+2][0] = fmaf(aw.z, vcur.x, cacc[g*4+2][0]);
            cacc[g*4+2][1] = fmaf(aw.z, vcur.y, cacc[g*4+2][1]);
            cacc[g*4+2][2] = fmaf(aw.z, vcur.z, cacc[g*4+2][2]);
            cacc[g*4+2][3] = fmaf(aw.z, vcur.w, cacc[g*4+2][3]);
            cacc[g*4+3][0] = fmaf(aw.w, vcur.x, cacc[g*4+3][0]);
            cacc[g*4+3][1] = fmaf(aw.w, vcur.y, cacc[g*4+3][1]);
            cacc[g*4+3][2] = fmaf(aw.w, vcur.z, cacc[g*4+3][2]);
            cacc[g*4+3][3] = fmaf(aw.w, vcur.w, cacc[g*4+3][3]);
        }
        vcur = vnxt;
    }
    // direct slab write: half h owns p=h (16 heads x 4 c per thread)
#pragma unroll
    for (int gh = 0; gh < 16; ++gh) {
        *(float4*)(ctxp + ((((size_t)sb*2 + half)*NB + b)*NH + gh)*NC + cq*4)
            = make_float4(cacc[gh][0], cacc[gh][1], cacc[gh][2], cacc[gh][3]);
    }
}

// Fused: slab-reduce ctxp + S-normalize + Wv GEMV + bias -> concat[p][b][d]
__global__ __launch_bounds__(256) void k_outhN(
    const float* __restrict__ ctxp, const float* __restrict__ Sp,
    const float* __restrict__ Wv, const float* __restrict__ bv,
    float* __restrict__ con)
{
    int b = blockIdx.y, p = blockIdx.z;
    int dx = blockIdx.x;
    int d = dx*256 + threadIdx.x;
    int h0 = dx*4;
    __shared__ float cl[4*NC];
    float Sinv[4];
#pragma unroll
    for (int j = 0; j < 4; ++j) {
        float a = 0.f;
        for (int sb = 0; sb < 16; ++sb)
            a += Sp[((size_t)b*16 + sb)*32 + p*16 + h0 + j];
        Sinv[j] = 1.f / a;
    }
#pragma unroll
    for (int hh = 0; hh < 4; ++hh) {
        for (int cc = threadIdx.x; cc < NC; cc += 256) {
            float a = 0.f;
#pragma unroll
            for (int ss = 0; ss < 16; ++ss)
                a += ctxp[((((size_t)ss*2 + p)*NB + b)*NH + h0 + hh)*NC + cc];
            cl[hh*NC + cc] = a * Sinv[hh];
        }
    }
    __syncthreads();
    const float* c2 = cl + ((threadIdx.x >> 6) << 10);
    float a0=0.f,a1=0.f,a2=0.f,a3=0.f;
    for (int c = 0; c < NC; c += 4) {
        a0 = fmaf(c2[c+0], Wv[(size_t)(c+0)*NC + d], a0);
        a1 = fmaf(c2[c+1], Wv[(size_t)(c+1)*NC + d], a1);
        a2 = fmaf(c2[c+2], Wv[(size_t)(c+2)*NC + d], a2);
        a3 = fmaf(c2[c+3], Wv[(size_t)(c+3)*NC + d], a3);
    }
    con[((size_t)p*NB + b)*NC + d] = (a0+a1)+(a2+a3) + bv[d];
}

// out[p][b][o] = concat[p][b][:] . Wo[:, o] + bo[o]
__global__ __launch_bounds__(256) void k_out(
    const float* __restrict__ con, const float* __restrict__ Wo,
    const float* __restrict__ bo, float* __restrict__ out)
{
    int b = blockIdx.y, p = blockIdx.z;
    int o = blockIdx.x*256 + threadIdx.x;
    __shared__ float cl[NC];
    for (int i = threadIdx.x; i < NC; i += 256)
        cl[i] = con[((size_t)p*NB + b)*NC + i];
    __syncthreads();
    float a0=0.f,a1=0.f,a2=0.f,a3=0.f;
    for (int m = 0; m < NC; m += 4) {
        a0 = fmaf(cl[m+0], Wo[(size_t)(m+0)*NC + o], a0);
        a1 = fmaf(cl[m+1], Wo[(size_t)(m+1)*NC + o], a1);
        a2 = fmaf(cl[m+2], Wo[(size_t)(m+2)*NC + o], a2);
        a3 = fmaf(cl[m+3], Wo[(size_t)(m+3)*NC + o], a3);
    }
    out[(size_t)p*NB*NC + (size_t)b*NC + o] = (a0+a1)+(a2+a3) + bo[o];
}

extern "C" void kernel_launch(void* const* d_in, const int* in_sizes, int n_in,
                              void* d_out, int out_size, void* d_ws, size_t ws_size,
                              hipStream_t stream)
{
    (void)in_sizes; (void)n_in; (void)out_size; (void)ws_size;
    const float* q  = (const float*)d_in[0];
    const float* k  = (const float*)d_in[1];
    const float* v  = (const float*)d_in[2];
    const float* Wq = (const float*)d_in[3];
    const float* bq = (const float*)d_in[4];
    const float* Wk = (const float*)d_in[5];
    const float* bk = (const float*)d_in[6];
    const float* Wv = (const float*)d_in[7];
    const float* bv = (const float*)d_in[8];
    const float* Wo = (const float*)d_in[9];
    const float* bo = (const float*)d_in[10];
    const void*  mk = d_in[11];

    float* ws   = (float*)d_ws;
    float* qhp  = ws + OFF_QHP;
    float* qkv  = ws + OFF_QK;
    float* qbv  = ws + OFF_QB;
    float* Sp   = ws + OFF_SP;
    float* ctxp = ws + OFF_CTXP;
    float* con  = ws + OFF_CON;
    float* out  = (float*)d_out;

    k_qh<<<dim3(8, 16), 128, 0, stream>>>(q, Wq, qhp);
    k_qk<<<dim3(16, 8), 128, 0, stream>>>(qhp, bq, Wk, bk, qkv, qbv);
    k_att<<<dim3(16, 16), 512, 0, stream>>>(k, v, qkv, qbv, mk, ctxp, Sp);
    k_outhN<<<dim3(4, NB, 2), 256, 0, stream>>>(ctxp, Sp, Wv, bv, con);
    k_out<<<dim3(4, NB, 2), 256, 0, stream>>>(con, Wo, bo, out);
}

// Round 14
// 250.860 us; speedup vs baseline: 1.1519x; 1.1519x over previous
//
#include <hip/hip_runtime.h>
#include <stdint.h>

#define NB 16
#define NS 4096
#define NH 16
#define NC 1024

// ---- workspace layout (float offsets) ----
#define OFF_QHP   0u          // 262144   qhp[cs16][b][d]
#define OFF_QK    262144u     // 262144   qk[b][h][c]
#define OFF_QB    524288u     // 256      qb[b][h]
#define OFF_SP    524608u     // 8192     Sp[b][sb16][ph32]
#define OFF_CTXP  532800u     // 8388608  ctxp[sb16*2+p][b][h][c]
#define OFF_CON   8921408u    // 32768    concat[p][b][dm]

// qhp[cs][b][d] = sum_{c in cs-chunk} q[b][c] * Wq[c][d]
__global__ __launch_bounds__(128) void k_qh(
    const float* __restrict__ q, const float* __restrict__ Wq, float* __restrict__ qhp)
{
    __shared__ float qs[64*16];   // [c][b]
    int dz = blockIdx.x, cs = blockIdx.y;
    int tid = threadIdx.x;
    int d = dz*128 + tid;
#pragma unroll
    for (int j = 0; j < 2; ++j) {
        int idx = j*128 + tid;
        int b = idx >> 4, c4 = (idx & 15) << 2;
        float4 t = *(const float4*)(q + (size_t)b*NC + cs*64 + c4);
        qs[(c4+0)*16 + b] = t.x; qs[(c4+1)*16 + b] = t.y;
        qs[(c4+2)*16 + b] = t.z; qs[(c4+3)*16 + b] = t.w;
    }
    __syncthreads();
    float acc[16];
#pragma unroll
    for (int b = 0; b < 16; ++b) acc[b] = 0.f;
#pragma unroll 4
    for (int c = 0; c < 64; ++c) {
        float w = Wq[(size_t)(cs*64 + c)*NC + d];
        const float4* qr = (const float4*)(qs + c*16);
        float4 q0 = qr[0], q1 = qr[1], q2 = qr[2], q3 = qr[3];
        acc[0]  = fmaf(w, q0.x, acc[0]);  acc[1]  = fmaf(w, q0.y, acc[1]);
        acc[2]  = fmaf(w, q0.z, acc[2]);  acc[3]  = fmaf(w, q0.w, acc[3]);
        acc[4]  = fmaf(w, q1.x, acc[4]);  acc[5]  = fmaf(w, q1.y, acc[5]);
        acc[6]  = fmaf(w, q1.z, acc[6]);  acc[7]  = fmaf(w, q1.w, acc[7]);
        acc[8]  = fmaf(w, q2.x, acc[8]);  acc[9]  = fmaf(w, q2.y, acc[9]);
        acc[10] = fmaf(w, q2.z, acc[10]); acc[11] = fmaf(w, q2.w, acc[11]);
        acc[12] = fmaf(w, q3.x, acc[12]); acc[13] = fmaf(w, q3.y, acc[13]);
        acc[14] = fmaf(w, q3.z, acc[14]); acc[15] = fmaf(w, q3.w, acc[15]);
    }
#pragma unroll
    for (int b = 0; b < 16; ++b) qhp[((size_t)cs*16 + b)*NC + d] = acc[b];
}

// qk[b][h][c] = sum_d qh[b][h64+d]*Wk[c][h64+d];  qh = sum_cs qhp + bq. qb = qh_h . bk_h
__global__ __launch_bounds__(128) void k_qk(
    const float* __restrict__ qhp, const float* __restrict__ bq,
    const float* __restrict__ Wk, const float* __restrict__ bk,
    float* __restrict__ qko, float* __restrict__ qbv)
{
    int h = blockIdx.x;
    int c = blockIdx.y*128 + threadIdx.x;
    __shared__ float qs[16*64];   // [b][dd]
    for (int j = 0; j < 8; ++j) {
        int idx = j*128 + threadIdx.x;
        int b = idx >> 6, dd = idx & 63;
        float a = bq[h*64 + dd];
#pragma unroll
        for (int cs = 0; cs < 16; ++cs) a += qhp[((size_t)cs*16 + b)*NC + h*64 + dd];
        qs[idx] = a;
    }
    __syncthreads();
    const float* wr = Wk + (size_t)c*NC + h*64;
    float acc[16];
#pragma unroll
    for (int b = 0; b < 16; ++b) acc[b] = 0.f;
#pragma unroll 4
    for (int d = 0; d < 64; ++d) {
        float w = wr[d];
#pragma unroll
        for (int b = 0; b < 16; ++b) acc[b] = fmaf(qs[b*64 + d], w, acc[b]);
    }
#pragma unroll
    for (int b = 0; b < 16; ++b) qko[((size_t)b*NH + h)*NC + c] = acc[b];
    if (blockIdx.y == 0 && threadIdx.x < 16) {
        int b = threadIdx.x; float a = 0.f;
        for (int d = 0; d < 64; ++d) a = fmaf(qs[b*64 + d], bk[h*64 + d], a);
        qbv[b*NH + h] = a;
    }
}

// Fused flash-style: scores + exp + mask + (att in LDS) + ctx + S.
// grid (sb=16, b=16) = 256 blocks x 512 thr = 1 block/CU, 2 waves/SIMD.
// Phase A: quad owns 8 rows x 4 heads; depth-2 k prefetch (A/B/T rotation).
// Phase B: half-block owns one p; v prefetch DEPTH 8 (vr/vn ring) to cover
// ~900cy HBM latency (R13: depth-1 left a ~900cy dependent stall per row).
#define QTS 20
#define SCOMP(BUF, W)                                                          \
    _Pragma("unroll")                                                          \
    for (int j = 0; j < 4; ++j) {                                              \
        const float* qp = qt + ((W)*16 + ph*4 + j)*QTS + hg*4;                 \
        float4 qv = *(const float4*)qp;                                        \
        _Pragma("unroll")                                                      \
        for (int i = 0; i < 8; ++i) {                                          \
            float kc = (j == 0) ? BUF[i].x : (j == 1) ? BUF[i].y               \
                     : (j == 2) ? BUF[i].z : BUF[i].w;                         \
            acc[i][0] = fmaf(kc, qv.x, acc[i][0]);                             \
            acc[i][1] = fmaf(kc, qv.y, acc[i][1]);                             \
            acc[i][2] = fmaf(kc, qv.z, acc[i][2]);                             \
            acc[i][3] = fmaf(kc, qv.w, acc[i][3]);                             \
        }                                                                      \
    }
__global__ __launch_bounds__(512, 2) void k_att(
    const float* __restrict__ kk, const float* __restrict__ vv,
    const float* __restrict__ qkm, const float* __restrict__ qbv,
    const void* __restrict__ mask, float* __restrict__ ctxp, float* __restrict__ Sp)
{
    __shared__ float qt[512*QTS];     // 40 KB q-stage
    __shared__ float attl[256*32];    // 32 KB, XOR-swizzled by row
    __shared__ float red[8][2][16];
    int sb = blockIdx.x, b = blockIdx.y;
    int tid = threadIdx.x;
    int ph = tid & 3, hg = (tid >> 2) & 3, rg = tid >> 4;  // rg in [0,32)
    int srow = sb*256 + rg*8;

    // inline mask dtype probe: 0=int32, 1=bytes, 2=float32
    int fl;
    {
        const uint4* mw = (const uint4*)mask;
        unsigned f = 0u, g = 0u;
#pragma unroll
        for (int j = 0; j < 8; ++j) {
            uint4 m4 = mw[j];
            f |= (m4.x == 0x3F800000u) | (m4.y == 0x3F800000u)
               | (m4.z == 0x3F800000u) | (m4.w == 0x3F800000u);
            g |= ((m4.x > 1u) & (m4.x != 0x3F800000u))
               | ((m4.y > 1u) & (m4.y != 0x3F800000u))
               | ((m4.z > 1u) & (m4.z != 0x3F800000u))
               | ((m4.w > 1u) & (m4.w != 0x3F800000u));
        }
        fl = f ? 2 : (g ? 1 : 0);
    }

    // ---------- Phase A: scores ----------
    const float* kr = kk + ((size_t)b*NS + srow)*NC + ph*4;
    float acc[8][4];
#pragma unroll
    for (int i = 0; i < 8; ++i)
#pragma unroll
        for (int j = 0; j < 4; ++j) acc[i][j] = 0.f;

    for (int cz = 0; cz < 2; ++cz) {
        __syncthreads();
#pragma unroll
        for (int j = 0; j < 16; ++j) {        // stage 512c x 16h
            int idx = j*512 + tid;
            int h = idx >> 9, c = idx & 511;
            qt[c*QTS + h] = qkm[((size_t)b*NH + h)*NC + cz*512 + c];
        }
        __syncthreads();
        const float* kc0 = kr + cz*512;
        float4 A[8], B[8], T[8];
#pragma unroll
        for (int i = 0; i < 8; ++i) A[i] = *(const float4*)(kc0 + i*NC);
#pragma unroll
        for (int i = 0; i < 8; ++i) B[i] = *(const float4*)(kc0 + i*NC + 16);
        for (int w = 0; w < 32; w += 2) {
            if (w + 2 < 32) {
#pragma unroll
                for (int i = 0; i < 8; ++i)
                    T[i] = *(const float4*)(kc0 + i*NC + (w+2)*16);
            }
            SCOMP(A, w);
            if (w + 3 < 32) {
#pragma unroll
                for (int i = 0; i < 8; ++i)
                    A[i] = *(const float4*)(kc0 + i*NC + (w+3)*16);
            }
            SCOMP(B, (w+1));
#pragma unroll
            for (int i = 0; i < 8; ++i) { B[i] = A[i]; A[i] = T[i]; }
        }
    }
#pragma unroll
    for (int i = 0; i < 8; ++i)
#pragma unroll
        for (int j = 0; j < 4; ++j) {
            acc[i][j] += __shfl_xor(acc[i][j], 1, 64);
            acc[i][j] += __shfl_xor(acc[i][j], 2, 64);
        }
    float d0[4], d1[4];
    if (ph == 0) {
#pragma unroll
        for (int j = 0; j < 4; ++j) { d0[j] = acc[0][j]; d1[j] = acc[1][j]; }
    } else if (ph == 1) {
#pragma unroll
        for (int j = 0; j < 4; ++j) { d0[j] = acc[2][j]; d1[j] = acc[3][j]; }
    } else if (ph == 2) {
#pragma unroll
        for (int j = 0; j < 4; ++j) { d0[j] = acc[4][j]; d1[j] = acc[5][j]; }
    } else {
#pragma unroll
        for (int j = 0; j < 4; ++j) { d0[j] = acc[6][j]; d1[j] = acc[7][j]; }
    }
    int lA = rg*8 + 2*ph, lB = lA + 1;
    int sA = sb*256 + lA, sB = sA + 1;
    unsigned mA = 0, mB = 0;
    if (fl == 1) {
        const uint8_t* mp = (const uint8_t*)mask + (size_t)(b*NH + hg*4)*NS;
#pragma unroll
        for (int j = 0; j < 4; ++j) {
            if (mp[(size_t)j*NS + sA]) mA |= (1u << j);
            if (mp[(size_t)j*NS + sB]) mB |= (1u << j);
        }
    } else if (fl == 2) {
        const float* mp = (const float*)mask + (size_t)(b*NH + hg*4)*NS;
#pragma unroll
        for (int j = 0; j < 4; ++j) {
            if (mp[(size_t)j*NS + sA] != 0.f) mA |= (1u << j);
            if (mp[(size_t)j*NS + sB] != 0.f) mB |= (1u << j);
        }
    } else {
        const int* mp = (const int*)mask + (size_t)(b*NH + hg*4)*NS;
#pragma unroll
        for (int j = 0; j < 4; ++j) {
            if (mp[(size_t)j*NS + sA]) mA |= (1u << j);
            if (mp[(size_t)j*NS + sB]) mB |= (1u << j);
        }
    }
    float p0a[4], p1a[4], p0b[4], p1b[4], r0[4], r1[4];
#pragma unroll
    for (int j = 0; j < 4; ++j) {
        float qb = qbv[b*NH + hg*4 + j];
        float va = (d0[j] + qb) * 0.125f;
        float vb2 = (d1[j] + qb) * 0.125f;
        p0a[j] = __expf(va);  p1a[j] = (mA >> j & 1u) ? 1.0f : p0a[j];
        p0b[j] = __expf(vb2); p1b[j] = (mB >> j & 1u) ? 1.0f : p0b[j];
        r0[j] = p0a[j] + p0b[j];
        r1[j] = p1a[j] + p1b[j];
    }
    // att -> LDS, XOR-swizzled: group G of row l at attl[l*32 + 4*(G ^ (l&7))]
    {
        int swA = (lA & 7) << 2, swB = (lB & 7) << 2;
        *(float4*)(attl + lA*32 + ((hg*4) ^ swA))        = make_float4(p0a[0], p0a[1], p0a[2], p0a[3]);
        *(float4*)(attl + lA*32 + ((16 + hg*4) ^ swA))   = make_float4(p1a[0], p1a[1], p1a[2], p1a[3]);
        *(float4*)(attl + lB*32 + ((hg*4) ^ swB))        = make_float4(p0b[0], p0b[1], p0b[2], p0b[3]);
        *(float4*)(attl + lB*32 + ((16 + hg*4) ^ swB))   = make_float4(p1b[0], p1b[1], p1b[2], p1b[3]);
    }
    // S partials
#pragma unroll
    for (int j = 0; j < 4; ++j) {
        r0[j] += __shfl_xor(r0[j], 1, 64);  r1[j] += __shfl_xor(r1[j], 1, 64);
        r0[j] += __shfl_xor(r0[j], 2, 64);  r1[j] += __shfl_xor(r1[j], 2, 64);
        r0[j] += __shfl_xor(r0[j], 16, 64); r1[j] += __shfl_xor(r1[j], 16, 64);
        r0[j] += __shfl_xor(r0[j], 32, 64); r1[j] += __shfl_xor(r1[j], 32, 64);
    }
    int wv = tid >> 6;
    if ((tid & 51) == 0) {
#pragma unroll
        for (int j = 0; j < 4; ++j) {
            red[wv][0][hg*4 + j] = r0[j];
            red[wv][1][hg*4 + j] = r1[j];
        }
    }
    __syncthreads();     // red + attl ready
    if (tid < 32) {
        int pa = tid >> 4, h = tid & 15;
        float a = 0.f;
#pragma unroll
        for (int w8 = 0; w8 < 8; ++w8) a += red[w8][pa][h];
        Sp[((size_t)b*16 + sb)*32 + tid] = a;
    }

    // ---------- Phase B: ctx (ph-split; depth-8 v prefetch ring) ----------
    int cq = tid & 255, half = tid >> 8;
    float cacc[16][4];
#pragma unroll
    for (int u = 0; u < 16; ++u)
#pragma unroll
        for (int j = 0; j < 4; ++j) cacc[u][j] = 0.f;
    const float* vb = vv + ((size_t)b*NS + sb*256)*NC + cq*4;
    float4 vr[8], vn[8];
#pragma unroll
    for (int i = 0; i < 8; ++i) vr[i] = *(const float4*)(vb + (size_t)i*NC);
    for (int r0q = 0; r0q < 256; r0q += 8) {
        if (r0q + 8 < 256) {
#pragma unroll
            for (int i = 0; i < 8; ++i)
                vn[i] = *(const float4*)(vb + (size_t)(r0q + 8 + i)*NC);
        }
#pragma unroll
        for (int i = 0; i < 8; ++i) {
            int r = r0q + i;
            const float* ar = attl + r*32;
            int lw = r & 7;
            float4 vcur = vr[i];
#pragma unroll
            for (int g = 0; g < 4; ++g) {
                int G = half*4 + g;
                float4 aw = *(const float4*)(ar + ((G ^ lw) << 2));
                cacc[g*4+0][0] = fmaf(aw.x, vcur.x, cacc[g*4+0][0]);
                cacc[g*4+0][1] = fmaf(aw.x, vcur.y, cacc[g*4+0][1]);
                cacc[g*4+0][2] = fmaf(aw.x, vcur.z, cacc[g*4+0][2]);
                cacc[g*4+0][3] = fmaf(aw.x, vcur.w, cacc[g*4+0][3]);
                cacc[g*4+1][0] = fmaf(aw.y, vcur.x, cacc[g*4+1][0]);
                cacc[g*4+1][1] = fmaf(aw.y, vcur.y, cacc[g*4+1][1]);
                cacc[g*4+1][2] = fmaf(aw.y, vcur.z, cacc[g*4+1][2]);
                cacc[g*4+1][3] = fmaf(aw.y, vcur.w, cacc[g*4+1][3]);
                cacc[g*4+2][0] = fmaf(aw.z, vcur.x, cacc[g*4+2][0]);
                cacc[g*4+2][1] = fmaf(aw.z, vcur.y, cacc[g*4+2][1]);
                cacc[g*4+2][2] = fmaf(aw.z, vcur.z, cacc[g*4+2][2]);
                cacc[g*4+2][3] = fmaf(aw.z, vcur.w, cacc[g*4+2][3]);
                cacc[g*4+3][0] = fmaf(aw.w, vcur.x, cacc[g*4+3][0]);
                cacc[g*4+3][1] = fmaf(aw.w, vcur.y, cacc[g*4+3][1]);
                cacc[g*4+3][2] = fmaf(aw.w, vcur.z, cacc[g*4+3][2]);
                cacc[g*4+3][3] = fmaf(aw.w, vcur.w, cacc[g*4+3][3]);
            }
        }
#pragma unroll
        for (int i = 0; i < 8; ++i) vr[i] = vn[i];
    }
    // direct slab write: half h owns p=h (16 heads x 4 c per thread)
#pragma unroll
    for (int gh = 0; gh < 16; ++gh) {
        *(float4*)(ctxp + ((((size_t)sb*2 + half)*NB + b)*NH + gh)*NC + cq*4)
            = make_float4(cacc[gh][0], cacc[gh][1], cacc[gh][2], cacc[gh][3]);
    }
}

// Fused: slab-reduce ctxp + S-normalize + Wv GEMV + bias -> concat[p][b][d]
__global__ __launch_bounds__(256) void k_outhN(
    const float* __restrict__ ctxp, const float* __restrict__ Sp,
    const float* __restrict__ Wv, const float* __restrict__ bv,
    float* __restrict__ con)
{
    int b = blockIdx.y, p = blockIdx.z;
    int dx = blockIdx.x;
    int d = dx*256 + threadIdx.x;
    int h0 = dx*4;
    __shared__ float cl[4*NC];
    float Sinv[4];
#pragma unroll
    for (int j = 0; j < 4; ++j) {
        float a = 0.f;
        for (int sb = 0; sb < 16; ++sb)
            a += Sp[((size_t)b*16 + sb)*32 + p*16 + h0 + j];
        Sinv[j] = 1.f / a;
    }
#pragma unroll
    for (int hh = 0; hh < 4; ++hh) {
        for (int cc = threadIdx.x; cc < NC; cc += 256) {
            float a = 0.f;
#pragma unroll
            for (int ss = 0; ss < 16; ++ss)
                a += ctxp[((((size_t)ss*2 + p)*NB + b)*NH + h0 + hh)*NC + cc];
            cl[hh*NC + cc] = a * Sinv[hh];
        }
    }
    __syncthreads();
    const float* c2 = cl + ((threadIdx.x >> 6) << 10);
    float a0=0.f,a1=0.f,a2=0.f,a3=0.f;
    for (int c = 0; c < NC; c += 4) {
        a0 = fmaf(c2[c+0], Wv[(size_t)(c+0)*NC + d], a0);
        a1 = fmaf(c2[c+1], Wv[(size_t)(c+1)*NC + d], a1);
        a2 = fmaf(c2[c+2], Wv[(size_t)(c+2)*NC + d], a2);
        a3 = fmaf(c2[c+3], Wv[(size_t)(c+3)*NC + d], a3);
    }
    con[((size_t)p*NB + b)*NC + d] = (a0+a1)+(a2+a3) + bv[d];
}

// out[p][b][o] = concat[p][b][:] . Wo[:, o] + bo[o]
__global__ __launch_bounds__(256) void k_out(
    const float* __restrict__ con, const float* __restrict__ Wo,
    const float* __restrict__ bo, float* __restrict__ out)
{
    int b = blockIdx.y, p = blockIdx.z;
    int o = blockIdx.x*256 + threadIdx.x;
    __shared__ float cl[NC];
    for (int i = threadIdx.x; i < NC; i += 256)
        cl[i] = con[((size_t)p*NB + b)*NC + i];
    __syncthreads();
    float a0=0.f,a1=0.f,a2=0.f,a3=0.f;
    for (int m = 0; m < NC; m += 4) {
        a0 = fmaf(cl[m+0], Wo[(size_t)(m+0)*NC + o], a0);
        a1 = fmaf(cl[m+1], Wo[(size_t)(m+1)*NC + o], a1);
        a2 = fmaf(cl[m+2], Wo[(size_t)(m+2)*NC + o], a2);
        a3 = fmaf(cl[m+3], Wo[(size_t)(m+3)*NC + o], a3);
    }
    out[(size_t)p*NB*NC + (size_t)b*NC + o] = (a0+a1)+(a2+a3) + bo[o];
}

extern "C" void kernel_launch(void* const* d_in, const int* in_sizes, int n_in,
                              void* d_out, int out_size, void* d_ws, size_t ws_size,
                              hipStream_t stream)
{
    (void)in_sizes; (void)n_in; (void)out_size; (void)ws_size;
    const float* q  = (const float*)d_in[0];
    const float* k  = (const float*)d_in[1];
    const float* v  = (const float*)d_in[2];
    const float* Wq = (const float*)d_in[3];
    const float* bq = (const float*)d_in[4];
    const float* Wk = (const float*)d_in[5];
    const float* bk = (const float*)d_in[6];
    const float* Wv = (const float*)d_in[7];
    const float* bv = (const float*)d_in[8];
    const float* Wo = (const float*)d_in[9];
    const float* bo = (const float*)d_in[10];
    const void*  mk = d_in[11];

    float* ws   = (float*)d_ws;
    float* qhp  = ws + OFF_QHP;
    float* qkv  = ws + OFF_QK;
    float* qbv  = ws + OFF_QB;
    float* Sp   = ws + OFF_SP;
    float* ctxp = ws + OFF_CTXP;
    float* con  = ws + OFF_CON;
    float* out  = (float*)d_out;

    k_qh<<<dim3(8, 16), 128, 0, stream>>>(q, Wq, qhp);
    k_qk<<<dim3(16, 8), 128, 0, stream>>>(qhp, bq, Wk, bk, qkv, qbv);
    k_att<<<dim3(16, 16), 512, 0, stream>>>(k, v, qkv, qbv, mk, ctxp, Sp);
    k_outhN<<<dim3(4, NB, 2), 256, 0, stream>>>(ctxp, Sp, Wv, bv, con);
    k_out<<<dim3(4, NB, 2), 256, 0, stream>>>(con, Wo, bo, out);
}